// Round 11
// baseline (217.132 us; speedup 1.0000x reference)
//
#include <hip/hip_runtime.h>
#include <hip/hip_bf16.h>
#include <math.h>
#include <stdint.h>

// InfoNCE fused: sim = A @ B^T / T  (8192x8192x512, fp32 in)
// loss = mean_i( logsumexp_j sim[i,j] - sim[i,i] )
// R11: int8 MFMA, double-buffered LDS with one-round-ahead prefetch
// (barrier drains a round-old load instead of a fresh one), reduce fused
// into gemm via atomic ticket (last block merges partials -> out).

#define NB 8192
#define DDIM 512
#define SPLITS 16
#define BM 128
#define BN 128
#define CPB (NB / SPLITS)        // 512 cols per block
#define TPB (CPB / BN)           // 4 col tiles per block
#define NROUND 32                // 4 tiles x 8 k-chunks of 64

#define DELTA 0.045f
#define INV_DELTA (1.0f / DELTA)
#define OUT_SCALE (DELTA * DELTA * 10.0f)   // dequant * 1/T

typedef unsigned char u8;
typedef __attribute__((ext_vector_type(4))) int i32x4;

// global -> LDS direct copy, 16B per lane: HW writes ldsbase + lane*16.
__device__ __forceinline__ void gl2lds16(const u8* g, const u8* l) {
  __builtin_amdgcn_global_load_lds(
      (__attribute__((address_space(1))) unsigned int*)(uintptr_t)g,
      (__attribute__((address_space(3))) unsigned int*)(unsigned int)(uintptr_t)l,
      16, 0, 0);
}

__device__ __forceinline__ unsigned pack4(float x0, float x1, float x2, float x3) {
  int q0 = min(127, max(-127, __float2int_rn(x0 * INV_DELTA)));
  int q1 = min(127, max(-127, __float2int_rn(x1 * INV_DELTA)));
  int q2 = min(127, max(-127, __float2int_rn(x2 * INV_DELTA)));
  int q3 = min(127, max(-127, __float2int_rn(x3 * INV_DELTA)));
  return (q0 & 0xFF) | ((q1 & 0xFF) << 8) | ((q2 & 0xFF) << 16) | ((q3 & 0xFF) << 24);
}

// One wave per row: quantize a & p rows to int8, diag dot in fp32; zero cnt.
__global__ void cvt_diag_kernel(const float* __restrict__ a, const float* __restrict__ p,
                                u8* __restrict__ aq, u8* __restrict__ pq,
                                float* __restrict__ diag, unsigned* __restrict__ cnt) {
  if (blockIdx.x == 0 && threadIdx.x == 0) cnt[0] = 0u;
  int row = (blockIdx.x * 256 + threadIdx.x) >> 6;
  int lane = threadIdx.x & 63;
  const float4* ar = (const float4*)(a + (size_t)row * DDIM + lane * 8);
  const float4* pr = (const float4*)(p + (size_t)row * DDIM + lane * 8);
  float4 a0 = ar[0], a1 = ar[1];
  float4 p0 = pr[0], p1 = pr[1];
  *(uint2*)(aq + (size_t)row * DDIM + lane * 8) =
      (uint2){pack4(a0.x, a0.y, a0.z, a0.w), pack4(a1.x, a1.y, a1.z, a1.w)};
  *(uint2*)(pq + (size_t)row * DDIM + lane * 8) =
      (uint2){pack4(p0.x, p0.y, p0.z, p0.w), pack4(p1.x, p1.y, p1.z, p1.w)};
  float s = a0.x * p0.x + a0.y * p0.y + a0.z * p0.z + a0.w * p0.w +
            a1.x * p1.x + a1.y * p1.y + a1.z * p1.z + a1.w * p1.w;
  for (int off = 32; off > 0; off >>= 1) s += __shfl_down(s, off);
  if (lane == 0) diag[row] = s * 10.0f;  // / T (exact fp32, not quantized)
}

__global__ __launch_bounds__(256, 4) void gemm_lse(
    const u8* __restrict__ Aq, const u8* __restrict__ Bq,
    float* __restrict__ partM, float* __restrict__ partL,
    const float* __restrict__ diag, unsigned* __restrict__ cnt,
    float* __restrict__ out) {
  // Double-buffered 64B-row chunks, R9's zero-conflict swizzle in each:
  // 16B octet o of row R stored at o ^ ((R>>1)&3).
  __shared__ u8 sA[2][BM * 64];       // 16 KB
  __shared__ u8 sB[2][BN * 64];       // 16 KB
  __shared__ float sPm[2 * TPB][BM];  // 4 KB per-tile (m)
  __shared__ float sPs[2 * TPB][BM];  // 4 KB per-tile (l)

  const int tid = threadIdx.x;
  const int wave = tid >> 6;
  const int lane = tid & 63;
  const int quad = lane >> 4;
  const int l16 = lane & 15;
  const int wr = wave >> 1, wc = wave & 1;  // 2x2 wave grid, each 64x64

  // XCD-aware remap: xcd = bid&7 gets row-tiles {xcd, xcd+8, ...}.
  const int bid = blockIdx.y * 64 + blockIdx.x;
  const int xcd = bid & 7;
  const int idx = bid >> 3;                 // 0..127
  const int rowTile = (idx & 7) * 8 + xcd;  // 0..63
  const int colSplit = idx >> 3;            // 0..15
  const int row0 = rowTile * BM;
  const int col0 = colSplit * CPB;

  // Staging source (per 64-k round): rows wave*32 + j*16 + rsub, stored
  // octet p = lane&3, source octet q = p ^ ((rsub>>1)&3).
  const int rsub = lane >> 2;
  const int qsrc = (lane & 3) ^ ((rsub >> 1) & 3);
  const u8* aCol = Aq + (size_t)(row0 + wave * 32 + rsub) * DDIM + qsrc * 16;
  const u8* bCol = Bq + (size_t)(col0 + wave * 32 + rsub) * DDIM + qsrc * 16;
  const int ldsOff = wave * 2048;

  // Fragment reads: row R = w*64 + i*16 + l16; k-octet quad at quad^((l16>>1)&3).
  const int sw = (l16 >> 1) & 3;
  const int fragA = (wr * 64 + l16) * 64 + ((quad ^ sw) * 16);
  const int fragB = (wc * 64 + l16) * 64 + ((quad ^ sw) * 16);

  // Round r (0..31): tile t = r>>3, k-chunk kk = (r&7)*64, buffer r&1.
#define STAGE(r)                                                        \
  do {                                                                  \
    int _t = (r) >> 3, _kk = ((r) & 7) << 6, _bf = (r) & 1;             \
    const u8* _a = aCol + _kk;                                          \
    const u8* _b = bCol + _t * (BN * DDIM) + _kk;                       \
    gl2lds16(_a, &sA[_bf][ldsOff]);                                     \
    gl2lds16(_a + 16 * DDIM, &sA[_bf][ldsOff + 1024]);                  \
    gl2lds16(_b, &sB[_bf][ldsOff]);                                     \
    gl2lds16(_b + 16 * DDIM, &sB[_bf][ldsOff + 1024]);                  \
  } while (0)

  STAGE(0);

  i32x4 acc[4][4];
#pragma unroll
  for (int mi = 0; mi < 4; ++mi)
#pragma unroll
    for (int ni = 0; ni < 4; ++ni) acc[mi][ni] = (i32x4){0, 0, 0, 0};

  for (int r = 0; r < NROUND; ++r) {
    const int buf = r & 1;
    __syncthreads();               // buf staged (issued one round ago);
                                   // also: all waves done reading buf^1
    if (r < NROUND - 1) STAGE(r + 1);  // prefetch into buf^1 (safe: see barrier)

    i32x4 af[4], bq[4];
#pragma unroll
    for (int i = 0; i < 4; ++i) {
      af[i] = *(const i32x4*)(&sA[buf][fragA + i * 16 * 64]);
      bq[i] = *(const i32x4*)(&sB[buf][fragB + i * 16 * 64]);
    }
#pragma unroll
    for (int mi = 0; mi < 4; ++mi)
#pragma unroll
      for (int ni = 0; ni < 4; ++ni)
        acc[mi][ni] =
            __builtin_amdgcn_mfma_i32_16x16x64_i8(af[mi], bq[ni], acc[mi][ni], 0, 0, 0);

    if ((r & 7) == 7) {
      // Per-tile LSE epilogue: dequant+1/T, shfl-merge over 16 l16 lanes,
      // stash (m,l) in LDS slot [t*2+wc].
      const int t = r >> 3;
#pragma unroll
      for (int mi = 0; mi < 4; ++mi) {
#pragma unroll
        for (int rr = 0; rr < 4; ++rr) {
          float v0 = (float)acc[mi][0][rr] * OUT_SCALE;
          float v1 = (float)acc[mi][1][rr] * OUT_SCALE;
          float v2 = (float)acc[mi][2][rr] * OUT_SCALE;
          float v3 = (float)acc[mi][3][rr] * OUT_SCALE;
          float mx = fmaxf(fmaxf(v0, v1), fmaxf(v2, v3));
          mx = fmaxf(mx, __shfl_xor(mx, 1));
          mx = fmaxf(mx, __shfl_xor(mx, 2));
          mx = fmaxf(mx, __shfl_xor(mx, 4));
          mx = fmaxf(mx, __shfl_xor(mx, 8));
          float s = __expf(v0 - mx) + __expf(v1 - mx) + __expf(v2 - mx) + __expf(v3 - mx);
          s += __shfl_xor(s, 1);
          s += __shfl_xor(s, 2);
          s += __shfl_xor(s, 4);
          s += __shfl_xor(s, 8);
          if (l16 == 0) {
            int rowl = wr * 64 + mi * 16 + quad * 4 + rr;
            sPm[t * 2 + wc][rowl] = mx;
            sPs[t * 2 + wc][rowl] = s;
          }
#pragma unroll
          for (int ni = 0; ni < 4; ++ni) acc[mi][ni][rr] = 0;  // reset for next tile
        }
      }
    }
  }

  // Block-level merge of the 8 tile partials -> one (m,l) per row.
  __syncthreads();
  if (tid < BM) {
    float m = sPm[0][tid], l = sPs[0][tid];
#pragma unroll
    for (int s = 1; s < 2 * TPB; ++s) {
      float om = sPm[s][tid], ol = sPs[s][tid];
      float nm = fmaxf(m, om);
      l = l * __expf(m - nm) + ol * __expf(om - nm);
      m = nm;
    }
    partM[(size_t)colSplit * NB + row0 + tid] = m;
    partL[(size_t)colSplit * NB + row0 + tid] = l;
  }
  __threadfence();   // release: partials device-visible before the ticket
  __syncthreads();
  if (tid == 0) {
    unsigned tk = atomicAdd(cnt, 1u);
    sPm[0][0] = (tk == 1023u) ? 1.0f : 0.0f;
  }
  __syncthreads();
  if (sPm[0][0] != 0.0f) {
    // Last block: final merge of all 16 splits + diag + mean -> out.
    __threadfence();  // acquire: see other blocks' partials
    float vsum = 0.f;
    for (int i = 0; i < NB / 256; ++i) {
      int row = i * 256 + tid;
      float M = -INFINITY;
#pragma unroll
      for (int s = 0; s < SPLITS; ++s) M = fmaxf(M, partM[(size_t)s * NB + row]);
      float L = 0.f;
#pragma unroll
      for (int s = 0; s < SPLITS; ++s)
        L += partL[(size_t)s * NB + row] * __expf(partM[(size_t)s * NB + row] - M);
      vsum += M + __logf(L) - diag[row];
    }
    for (int off = 32; off > 0; off >>= 1) vsum += __shfl_down(vsum, off);
    if ((tid & 63) == 0) sPs[0][tid >> 6] = vsum;
    __syncthreads();
    if (tid == 0)
      out[0] = (sPs[0][0] + sPs[0][1] + sPs[0][2] + sPs[0][3]) * (1.0f / (float)NB);
  }
#undef STAGE
}

extern "C" void kernel_launch(void* const* d_in, const int* in_sizes, int n_in,
                              void* d_out, int out_size, void* d_ws, size_t ws_size,
                              hipStream_t stream) {
  const float* anchor = (const float*)d_in[0];
  const float* positive = (const float*)d_in[1];
  float* out = (float*)d_out;

  char* ws = (char*)d_ws;
  u8* Aq = (u8*)ws;                                      // 4 MB
  u8* Bq = (u8*)(ws + (size_t)4194304);                  // 4 MB
  float* diag = (float*)(ws + (size_t)8388608);          // 32 KB
  float* partM = (float*)(ws + (size_t)8388608 + 32768);             // 512 KB
  float* partL = (float*)(ws + (size_t)8388608 + 32768 + (size_t)SPLITS * NB * 4);
  unsigned* cnt = (unsigned*)(ws + (size_t)8388608 + 32768 + (size_t)2 * SPLITS * NB * 4);

  cvt_diag_kernel<<<NB / 4, 256, 0, stream>>>(anchor, positive, Aq, Bq, diag, cnt);
  gemm_lse<<<dim3(64, SPLITS), 256, 0, stream>>>(Aq, Bq, partM, partL, diag, cnt, out);
}

// Round 12
// 206.422 us; speedup vs baseline: 1.0519x; 1.0519x over previous
//
#include <hip/hip_runtime.h>
#include <hip/hip_bf16.h>
#include <math.h>
#include <stdint.h>

// InfoNCE fused: sim = A @ B^T / T  (8192x8192x512, fp32 in)
// loss = mean_i( logsumexp_j sim[i,j] - sim[i,i] )
// R12: int8 MFMA, R10's 2-barrier cadence, + persistent 64KB A-tile in LDS
// (staged once, half the per-round staging), + per-lane register LSE
// (one shfl merge per block; safe under the 256-VGPR cap at 2 blocks/CU),
// + ticket-fused final reduce (2 dispatches).

#define NB 8192
#define DDIM 512
#define SPLITS 16
#define BM 128
#define BN 128
#define CPB (NB / SPLITS)        // 512 cols per block
#define TPB (CPB / BN)           // 4 col tiles per block

#define DELTA 0.045f
#define INV_DELTA (1.0f / DELTA)
#define OUT_SCALE (DELTA * DELTA * 10.0f)   // dequant * 1/T

typedef unsigned char u8;
typedef __attribute__((ext_vector_type(4))) int i32x4;

// global -> LDS direct copy, 16B per lane: HW writes ldsbase + lane*16.
__device__ __forceinline__ void gl2lds16(const u8* g, const u8* l) {
  __builtin_amdgcn_global_load_lds(
      (__attribute__((address_space(1))) unsigned int*)(uintptr_t)g,
      (__attribute__((address_space(3))) unsigned int*)(unsigned int)(uintptr_t)l,
      16, 0, 0);
}

__device__ __forceinline__ unsigned pack4(float x0, float x1, float x2, float x3) {
  int q0 = min(127, max(-127, __float2int_rn(x0 * INV_DELTA)));
  int q1 = min(127, max(-127, __float2int_rn(x1 * INV_DELTA)));
  int q2 = min(127, max(-127, __float2int_rn(x2 * INV_DELTA)));
  int q3 = min(127, max(-127, __float2int_rn(x3 * INV_DELTA)));
  return (q0 & 0xFF) | ((q1 & 0xFF) << 8) | ((q2 & 0xFF) << 16) | ((q3 & 0xFF) << 24);
}

// One wave per row: quantize a & p rows to int8, diag dot in fp32; zero cnt.
__global__ void cvt_diag_kernel(const float* __restrict__ a, const float* __restrict__ p,
                                u8* __restrict__ aq, u8* __restrict__ pq,
                                float* __restrict__ diag, unsigned* __restrict__ cnt) {
  if (blockIdx.x == 0 && threadIdx.x == 0) cnt[0] = 0u;
  int row = (blockIdx.x * 256 + threadIdx.x) >> 6;
  int lane = threadIdx.x & 63;
  const float4* ar = (const float4*)(a + (size_t)row * DDIM + lane * 8);
  const float4* pr = (const float4*)(p + (size_t)row * DDIM + lane * 8);
  float4 a0 = ar[0], a1 = ar[1];
  float4 p0 = pr[0], p1 = pr[1];
  *(uint2*)(aq + (size_t)row * DDIM + lane * 8) =
      (uint2){pack4(a0.x, a0.y, a0.z, a0.w), pack4(a1.x, a1.y, a1.z, a1.w)};
  *(uint2*)(pq + (size_t)row * DDIM + lane * 8) =
      (uint2){pack4(p0.x, p0.y, p0.z, p0.w), pack4(p1.x, p1.y, p1.z, p1.w)};
  float s = a0.x * p0.x + a0.y * p0.y + a0.z * p0.z + a0.w * p0.w +
            a1.x * p1.x + a1.y * p1.y + a1.z * p1.z + a1.w * p1.w;
  for (int off = 32; off > 0; off >>= 1) s += __shfl_down(s, off);
  if (lane == 0) diag[row] = s * 10.0f;  // / T (exact fp32, not quantized)
}

__global__ __launch_bounds__(256, 2) void gemm_lse(
    const u8* __restrict__ Aq, const u8* __restrict__ Bq,
    float* __restrict__ partM, float* __restrict__ partL,
    const float* __restrict__ diag, unsigned* __restrict__ cnt,
    float* __restrict__ out) {
  // sA: persistent full A tile, 128 rows x 512 k (64 KB). Octet p of row R
  // stored at p ^ (R&31) -> fragment reads <=2-way bank alias (free).
  // sB: two 64-k halves per round, R9's zero-conflict 64B-row swizzle.
  __shared__ u8 sA[BM * DDIM];     // 64 KB
  __shared__ u8 sB[2][BN * 64];    // 16 KB (aliased as merge scratch at end)

  const int tid = threadIdx.x;
  const int wave = tid >> 6;
  const int lane = tid & 63;
  const int quad = lane >> 4;
  const int l16 = lane & 15;
  const int wr = wave >> 1, wc = wave & 1;  // 2x2 wave grid, each 64x64

  // XCD-aware remap: xcd = bid&7 gets row-tiles {xcd, xcd+8, ...}.
  const int bid = blockIdx.y * 64 + blockIdx.x;
  const int xcd = bid & 7;
  const int idx = bid >> 3;                 // 0..127
  const int rowTile = (idx & 7) * 8 + xcd;  // 0..63
  const int colSplit = idx >> 3;            // 0..15
  const int row0 = rowTile * BM;
  const int col0 = colSplit * CPB;

  // ---- Stage full A tile once: 64 wave-loads (16/wave), 2 rows each. ----
  for (int i = 0; i < 16; ++i) {
    int R0 = wave * 32 + i * 2;               // rows R0, R0+1
    int R = R0 + (lane >> 5);
    int p = lane & 31;
    int q = p ^ (R & 31);
    gl2lds16(Aq + (size_t)(row0 + R) * DDIM + q * 16, &sA[R0 * DDIM]);
  }

  // B staging (per half h, j in {0,1}): rows wave*32 + j*16 + rsub, stored
  // octet p = lane&3, source octet q = p ^ ((rsub>>1)&3).
  const int rsub = lane >> 2;
  const int qsrc = (lane & 3) ^ ((rsub >> 1) & 3);
  const u8* bCol = Bq + (size_t)(col0 + wave * 32 + rsub) * DDIM + qsrc * 16;
  const int ldsOff = wave * 2048;

  // A fragment offsets: row R = wr*64 + mi*16 + l16; for k-chunk kc, octet
  // o = kc*4 + quad stored at o ^ (R&31); R&31 = (mi&1)*16 + l16.
  const int xaE = l16;          // mi even
  const int xaO = 16 + l16;     // mi odd
  // B fragment: row 64B, octet quad stored at quad ^ ((l16>>1)&3).
  const int swB = (l16 >> 1) & 3;
  const int fragB = (wc * 64 + l16) * 64 + ((quad ^ swB) * 16);

  // Per-lane running LSE over this block's 512 cols (same rows all tiles).
  float rm[4][4], rl[4][4];
#pragma unroll
  for (int mi = 0; mi < 4; ++mi)
#pragma unroll
    for (int r = 0; r < 4; ++r) { rm[mi][r] = -INFINITY; rl[mi][r] = 0.f; }

  for (int t = 0; t < TPB; ++t) {
    const u8* bT = bCol + (size_t)t * BN * DDIM;

    i32x4 acc[4][4];
#pragma unroll
    for (int mi = 0; mi < 4; ++mi)
#pragma unroll
      for (int ni = 0; ni < 4; ++ni) acc[mi][ni] = (i32x4){0, 0, 0, 0};

    for (int rr = 0; rr < 4; ++rr) {          // 128-k rounds
      __syncthreads();  // previous round's B readers done (and A staged, rr=0)
#pragma unroll
      for (int h = 0; h < 2; ++h)
#pragma unroll
        for (int j = 0; j < 2; ++j)
          gl2lds16(bT + j * 16 * DDIM + rr * 128 + h * 64, &sB[h][ldsOff + j * 1024]);
      __syncthreads();  // staging complete (barrier drains vmcnt)

#pragma unroll
      for (int h = 0; h < 2; ++h) {
        const int kc = rr * 2 + h;            // 64-k chunk index 0..7
        i32x4 af[4], bq[4];
#pragma unroll
        for (int i = 0; i < 4; ++i) {
          int x = (i & 1) ? xaO : xaE;
          int pos = (kc * 4 + quad) ^ x;
          af[i] = *(const i32x4*)(&sA[(wr * 64 + i * 16 + l16) * DDIM + pos * 16]);
          bq[i] = *(const i32x4*)(&sB[h][fragB + i * 16 * 64]);
        }
#pragma unroll
        for (int mi = 0; mi < 4; ++mi)
#pragma unroll
          for (int ni = 0; ni < 4; ++ni)
            acc[mi][ni] =
                __builtin_amdgcn_mfma_i32_16x16x64_i8(af[mi], bq[ni], acc[mi][ni], 0, 0, 0);
      }
    }

    // Per-tile LSE folded into per-lane running state (no cross-lane work).
#pragma unroll
    for (int mi = 0; mi < 4; ++mi) {
#pragma unroll
      for (int r = 0; r < 4; ++r) {
        float v0 = (float)acc[mi][0][r] * OUT_SCALE;
        float v1 = (float)acc[mi][1][r] * OUT_SCALE;
        float v2 = (float)acc[mi][2][r] * OUT_SCALE;
        float v3 = (float)acc[mi][3][r] * OUT_SCALE;
        float vm = fmaxf(fmaxf(v0, v1), fmaxf(v2, v3));
        float nm = fmaxf(rm[mi][r], vm);
        rl[mi][r] = rl[mi][r] * __expf(rm[mi][r] - nm) +
                    (__expf(v0 - nm) + __expf(v1 - nm) + __expf(v2 - nm) + __expf(v3 - nm));
        rm[mi][r] = nm;
      }
    }
  }

  // Cross-lane merge over l16 (once per block), then cross-wc via LDS.
  float* sPm = (float*)&sB[0][0];     // [2][BM] alias (reads done, barrier below)
  float* sPs = (float*)&sB[0][1024];
  __syncthreads();
#pragma unroll
  for (int mi = 0; mi < 4; ++mi) {
#pragma unroll
    for (int r = 0; r < 4; ++r) {
      float m = rm[mi][r], l = rl[mi][r];
#pragma unroll
      for (int mask = 1; mask < 16; mask <<= 1) {
        float om = __shfl_xor(m, mask);
        float ol = __shfl_xor(l, mask);
        float nm = fmaxf(m, om);
        l = l * __expf(m - nm) + ol * __expf(om - nm);
        m = nm;
      }
      if (l16 == 0) {
        int rowl = wr * 64 + mi * 16 + quad * 4 + r;
        sPm[wc * BM + rowl] = m;
        sPs[wc * BM + rowl] = l;
      }
    }
  }
  __syncthreads();
  if (tid < BM) {
    float m0 = sPm[tid], m1 = sPm[BM + tid];
    float s0 = sPs[tid], s1 = sPs[BM + tid];
    float nm = fmaxf(m0, m1);
    partM[(size_t)colSplit * NB + row0 + tid] = nm;
    partL[(size_t)colSplit * NB + row0 + tid] = s0 * __expf(m0 - nm) + s1 * __expf(m1 - nm);
  }
  __threadfence();   // release: partials device-visible before the ticket
  __syncthreads();
  if (tid == 0) {
    unsigned tk = atomicAdd(cnt, 1u);
    sPm[0] = (tk == 1023u) ? 1.0f : 0.0f;
  }
  __syncthreads();
  if (sPm[0] != 0.0f) {
    // Last block: final merge of all 16 splits + diag + mean -> out.
    __threadfence();  // acquire: see other blocks' partials
    float vsum = 0.f;
    for (int i = 0; i < NB / 256; ++i) {
      int row = i * 256 + tid;
      float M = -INFINITY;
#pragma unroll
      for (int s = 0; s < SPLITS; ++s) M = fmaxf(M, partM[(size_t)s * NB + row]);
      float L = 0.f;
#pragma unroll
      for (int s = 0; s < SPLITS; ++s)
        L += partL[(size_t)s * NB + row] * __expf(partM[(size_t)s * NB + row] - M);
      vsum += M + __logf(L) - diag[row];
    }
    for (int off = 32; off > 0; off >>= 1) vsum += __shfl_down(vsum, off);
    __syncthreads();
    if ((tid & 63) == 0) sPs[tid >> 6] = vsum;
    __syncthreads();
    if (tid == 0)
      out[0] = (sPs[0] + sPs[1] + sPs[2] + sPs[3]) * (1.0f / (float)NB);
  }
}

extern "C" void kernel_launch(void* const* d_in, const int* in_sizes, int n_in,
                              void* d_out, int out_size, void* d_ws, size_t ws_size,
                              hipStream_t stream) {
  const float* anchor = (const float*)d_in[0];
  const float* positive = (const float*)d_in[1];
  float* out = (float*)d_out;

  char* ws = (char*)d_ws;
  u8* Aq = (u8*)ws;                                      // 4 MB
  u8* Bq = (u8*)(ws + (size_t)4194304);                  // 4 MB
  float* diag = (float*)(ws + (size_t)8388608);          // 32 KB
  float* partM = (float*)(ws + (size_t)8388608 + 32768);             // 512 KB
  float* partL = (float*)(ws + (size_t)8388608 + 32768 + (size_t)SPLITS * NB * 4);
  unsigned* cnt = (unsigned*)(ws + (size_t)8388608 + 32768 + (size_t)2 * SPLITS * NB * 4);

  cvt_diag_kernel<<<NB / 4, 256, 0, stream>>>(anchor, positive, Aq, Bq, diag, cnt);
  gemm_lse<<<dim3(64, SPLITS), 256, 0, stream>>>(Aq, Bq, partM, partL, diag, cnt, out);
}